// Round 1
// baseline (2115.321 us; speedup 1.0000x reference)
//
#include <hip/hip_runtime.h>
#include <hip/hip_bf16.h>
#include <math.h>

#define DEPTH 6
#define DIM   768
#define HEADS 12
#define DH    64
#define NCTX  1024
#define BATCH 8
#define ROWS  (BATCH*NCTX)   /* 8192 */
#define DIM3  (3*DIM)        /* 2304 */
#define DIMF  (4*DIM)        /* 3072 */
#define LNEPS 1e-5f

typedef __attribute__((ext_vector_type(8))) short short8;
typedef __attribute__((ext_vector_type(4))) float floatx4;
using bf16 = __hip_bfloat16;

static __device__ __forceinline__ bf16 f2bf(float v){ return __float2bfloat16(v); }

// ---------------------------------------------------------------------------
// W [L][K][N] fp32  ->  WT [L][N][K] bf16   (tiled transpose via LDS)
// grid (N/32, K/32, L), block (32,8)
// ---------------------------------------------------------------------------
__global__ void k_transpose_convert(const float* __restrict__ W, bf16* __restrict__ WT,
                                    int K, int N) {
    __shared__ float tile[32][33];
    int l = blockIdx.z;
    const float* Wl = W + (size_t)l * K * N;
    bf16* WTl = WT + (size_t)l * K * N;
    int n0 = blockIdx.x * 32, k0 = blockIdx.y * 32;
    int tx = threadIdx.x, ty = threadIdx.y;
#pragma unroll
    for (int i = 0; i < 4; i++)
        tile[ty + i*8][tx] = Wl[(size_t)(k0 + ty + i*8) * N + n0 + tx];
    __syncthreads();
#pragma unroll
    for (int i = 0; i < 4; i++)
        WTl[(size_t)(n0 + ty + i*8) * K + k0 + tx] = f2bf(tile[tx][ty + i*8]);
}

// ---------------------------------------------------------------------------
// LayerNorm: x fp32 [ROWS][DIM] -> y bf16 [ROWS][DIM].  1 block / row.
// ---------------------------------------------------------------------------
__global__ __launch_bounds__(256) void k_layernorm(const float* __restrict__ x,
                                                   const float* __restrict__ g,
                                                   const float* __restrict__ b,
                                                   bf16* __restrict__ y) {
    int row = blockIdx.x;
    const float* xr = x + (size_t)row * DIM;
    int t = threadIdx.x;
    float v[3];
    float s = 0.f, s2 = 0.f;
#pragma unroll
    for (int i = 0; i < 3; i++) { v[i] = xr[t + i*256]; s += v[i]; s2 += v[i]*v[i]; }
#pragma unroll
    for (int m = 1; m < 64; m <<= 1) { s += __shfl_xor(s, m); s2 += __shfl_xor(s2, m); }
    __shared__ float ss[4], ss2[4];
    int w = t >> 6;
    if ((t & 63) == 0) { ss[w] = s; ss2[w] = s2; }
    __syncthreads();
    s  = ss[0] + ss[1] + ss[2] + ss[3];
    s2 = ss2[0] + ss2[1] + ss2[2] + ss2[3];
    float mu  = s * (1.f / DIM);
    float var = s2 * (1.f / DIM) - mu * mu;
    float rs  = rsqrtf(var + LNEPS);
    bf16* yr = y + (size_t)row * DIM;
#pragma unroll
    for (int i = 0; i < 3; i++) {
        int c = t + i*256;
        yr[c] = f2bf((v[i] - mu) * rs * g[c] + b[c]);
    }
}

// ---------------------------------------------------------------------------
// GEMM: C[M][N] = act(A[M][K] @ WT[N][K]^T + bias)
// MODE 0: bf16 store (qkv);  MODE 1: bf16 store with exact GELU (h);
// MODE 2: fp32 residual add into outf (x += ...)
// BM=BN=128, BK=32, 4 waves (2x2) of 64x64.  grid (N/128, M/128), block 256.
// ---------------------------------------------------------------------------
template<int MODE>
__global__ __launch_bounds__(256) void k_gemm(const bf16* __restrict__ A,
                                              const bf16* __restrict__ WT,
                                              const float* __restrict__ bias,
                                              bf16* __restrict__ outb,
                                              float* __restrict__ outf,
                                              int N, int K) {
    __shared__ __align__(16) bf16 As[128][40];
    __shared__ __align__(16) bf16 Bs[128][40];
    int m0 = blockIdx.y * 128, n0 = blockIdx.x * 128;
    int t = threadIdx.x;
    int lane = t & 63, w = t >> 6;
    int wr = (w >> 1) * 64, wc = (w & 1) * 64;
    int lr = lane & 15, lg = lane >> 4;
    floatx4 acc[4][4] = {};
    for (int k0 = 0; k0 < K; k0 += 32) {
#pragma unroll
        for (int it = 0; it < 2; it++) {
            int c = it * 256 + t;              // 512 chunks of 16B
            int row = c >> 2, col = (c & 3) * 8;
            *(uint4*)&As[row][col] = *(const uint4*)&A [(size_t)(m0 + row) * K + k0 + col];
            *(uint4*)&Bs[row][col] = *(const uint4*)&WT[(size_t)(n0 + row) * K + k0 + col];
        }
        __syncthreads();
        short8 af[4], bfr[4];
#pragma unroll
        for (int i = 0; i < 4; i++) af[i]  = *(const short8*)&As[wr + i*16 + lr][lg * 8];
#pragma unroll
        for (int j = 0; j < 4; j++) bfr[j] = *(const short8*)&Bs[wc + j*16 + lr][lg * 8];
#pragma unroll
        for (int i = 0; i < 4; i++)
#pragma unroll
            for (int j = 0; j < 4; j++)
                acc[i][j] = __builtin_amdgcn_mfma_f32_16x16x32_bf16(af[i], bfr[j], acc[i][j], 0, 0, 0);
        __syncthreads();
    }
#pragma unroll
    for (int i = 0; i < 4; i++)
#pragma unroll
        for (int j = 0; j < 4; j++)
#pragma unroll
            for (int r = 0; r < 4; r++) {
                int row = m0 + wr + i*16 + lg*4 + r;
                int col = n0 + wc + j*16 + lr;
                float vv = acc[i][j][r] + bias[col];
                if (MODE == 0) {
                    outb[(size_t)row * N + col] = f2bf(vv);
                } else if (MODE == 1) {
                    outb[(size_t)row * N + col] = f2bf(0.5f * vv * (1.f + erff(vv * 0.70710678118f)));
                } else {
                    outf[(size_t)row * N + col] += vv;
                }
            }
}

// ---------------------------------------------------------------------------
// Flash attention, fused residual add into x (fp32).
// qkv bf16 [ROWS][2304]: cols [0,768)=Q, [768,1536)=K, [1536,2304)=V, head h at h*64.
// grid (8 qtiles, HEADS, BATCH), block 256 (4 waves x 32 q-rows = QBLK 128), KVBLK 64.
// ---------------------------------------------------------------------------
__global__ __launch_bounds__(256) void k_attn(const bf16* __restrict__ qkv,
                                              float* __restrict__ x) {
    int qt = blockIdx.x, h = blockIdx.y, b = blockIdx.z;
    int t = threadIdx.x, lane = t & 63, w = t >> 6;
    int lr = lane & 15, lg = lane >> 4;
    const size_t bn0 = (size_t)b * NCTX;
    const bf16* Qg = qkv + bn0 * DIM3 + h * DH;
    const bf16* Kg = Qg + DIM;
    const bf16* Vg = Qg + 2 * DIM;
    int q0 = qt * 128 + w * 32;

    short8 qf[2][2];
#pragma unroll
    for (int i = 0; i < 2; i++)
#pragma unroll
        for (int s = 0; s < 2; s++)
            qf[i][s] = *(const short8*)&Qg[(size_t)(q0 + i*16 + lr) * DIM3 + s*32 + lg*8];

    __shared__ __align__(16) bf16 Ks[64][72];
    __shared__ __align__(16) bf16 VTs[64][72];
    __shared__ __align__(16) bf16 Ps[4][32][72];

    floatx4 oacc[2][4] = {};
    float mrow[2][4], lrow[2][4];
#pragma unroll
    for (int i = 0; i < 2; i++)
#pragma unroll
        for (int r = 0; r < 4; r++) { mrow[i][r] = -1e30f; lrow[i][r] = 0.f; }
    const float scale = 0.036084391824351615f; /* 768^-0.5 (full dim per reference) */

    for (int kt = 0; kt < 16; kt++) {
        __syncthreads();
        int kv0 = kt * 64;
#pragma unroll
        for (int it = 0; it < 2; it++) {
            int c = it * 256 + t;              // 512 chunks: 64 rows x 8
            int row = c >> 3, col = (c & 7) * 8;
            *(uint4*)&Ks[row][col] = *(const uint4*)&Kg[(size_t)(kv0 + row) * DIM3 + col];
            uint4 vv = *(const uint4*)&Vg[(size_t)(kv0 + row) * DIM3 + col];
            const bf16* vp = (const bf16*)&vv;
#pragma unroll
            for (int e = 0; e < 8; e++) VTs[col + e][row] = vp[e];
        }
        __syncthreads();

        floatx4 sacc[2][4] = {};
#pragma unroll
        for (int j = 0; j < 4; j++) {
            short8 kf[2];
#pragma unroll
            for (int s = 0; s < 2; s++) kf[s] = *(const short8*)&Ks[j*16 + lr][s*32 + lg*8];
#pragma unroll
            for (int i = 0; i < 2; i++)
#pragma unroll
                for (int s = 0; s < 2; s++)
                    sacc[i][j] = __builtin_amdgcn_mfma_f32_16x16x32_bf16(qf[i][s], kf[s], sacc[i][j], 0, 0, 0);
        }

#pragma unroll
        for (int i = 0; i < 2; i++)
#pragma unroll
            for (int r = 0; r < 4; r++) {
                float mx = -1e30f;
#pragma unroll
                for (int j = 0; j < 4; j++) mx = fmaxf(mx, sacc[i][j][r] * scale);
#pragma unroll
                for (int m = 1; m < 16; m <<= 1) mx = fmaxf(mx, __shfl_xor(mx, m));
                float mnew = fmaxf(mrow[i][r], mx);
                float corr = __expf(mrow[i][r] - mnew);
                mrow[i][r] = mnew;
                float sum = 0.f;
#pragma unroll
                for (int j = 0; j < 4; j++) {
                    float pv = __expf(sacc[i][j][r] * scale - mnew);
                    sum += pv;
                    Ps[w][i*16 + lg*4 + r][j*16 + lr] = f2bf(pv);
                }
#pragma unroll
                for (int m = 1; m < 16; m <<= 1) sum += __shfl_xor(sum, m);
                lrow[i][r] = lrow[i][r] * corr + sum;
#pragma unroll
                for (int j = 0; j < 4; j++) oacc[i][j][r] *= corr;
            }
        __syncthreads();   // P (and keeps block lockstep before next stage)

#pragma unroll
        for (int s = 0; s < 2; s++) {
            short8 pa[2];
#pragma unroll
            for (int i = 0; i < 2; i++) pa[i] = *(const short8*)&Ps[w][i*16 + lr][s*32 + lg*8];
#pragma unroll
            for (int j = 0; j < 4; j++) {
                short8 vbf = *(const short8*)&VTs[j*16 + lr][s*32 + lg*8];
#pragma unroll
                for (int i = 0; i < 2; i++)
                    oacc[i][j] = __builtin_amdgcn_mfma_f32_16x16x32_bf16(pa[i], vbf, oacc[i][j], 0, 0, 0);
            }
        }
    }

    float* xr = x + bn0 * DIM + (size_t)h * DH;
#pragma unroll
    for (int i = 0; i < 2; i++)
#pragma unroll
        for (int j = 0; j < 4; j++)
#pragma unroll
            for (int r = 0; r < 4; r++) {
                int row = q0 + i*16 + lg*4 + r;
                int col = j*16 + lr;
                xr[(size_t)row * DIM + col] += oacc[i][j][r] / lrow[i][r];
            }
}

// ---------------------------------------------------------------------------
extern "C" void kernel_launch(void* const* d_in, const int* in_sizes, int n_in,
                              void* d_out, int out_size, void* d_ws, size_t ws_size,
                              hipStream_t stream) {
    const float* x_in  = (const float*)d_in[0];
    const float* ln1_g = (const float*)d_in[1];
    const float* ln1_b = (const float*)d_in[2];
    const float* wqkv  = (const float*)d_in[3];
    const float* bqkv  = (const float*)d_in[4];
    const float* ln2_g = (const float*)d_in[5];
    const float* ln2_b = (const float*)d_in[6];
    const float* w1    = (const float*)d_in[7];
    const float* b1    = (const float*)d_in[8];
    const float* w2    = (const float*)d_in[9];
    const float* b2    = (const float*)d_in[10];
    float* x = (float*)d_out;

    char* ws = (char*)d_ws;
    size_t off = 0;
    auto alloc = [&](size_t bytes) { void* p = ws + off; off += (bytes + 255) & ~255ull; return p; };
    bf16* wqkvT = (bf16*)alloc((size_t)DEPTH * DIM * DIM3 * 2);
    bf16* w1T   = (bf16*)alloc((size_t)DEPTH * DIM * DIMF * 2);
    bf16* w2T   = (bf16*)alloc((size_t)DEPTH * DIMF * DIM * 2);
    bf16* xn    = (bf16*)alloc((size_t)ROWS * DIM * 2);
    bf16* qkvh  = (bf16*)alloc((size_t)ROWS * DIMF * 2);  // shared: qkv (2304) / h (3072)
    if (off > ws_size) return;  // workspace too small -> fail visibly

    hipMemcpyAsync(x, x_in, (size_t)ROWS * DIM * 4, hipMemcpyDeviceToDevice, stream);

    k_transpose_convert<<<dim3(DIM3/32, DIM/32,  DEPTH), dim3(32, 8), 0, stream>>>(wqkv, wqkvT, DIM,  DIM3);
    k_transpose_convert<<<dim3(DIMF/32, DIM/32,  DEPTH), dim3(32, 8), 0, stream>>>(w1,   w1T,   DIM,  DIMF);
    k_transpose_convert<<<dim3(DIM/32,  DIMF/32, DEPTH), dim3(32, 8), 0, stream>>>(w2,   w2T,   DIMF, DIM);

    for (int l = 0; l < DEPTH; l++) {
        k_layernorm<<<ROWS, 256, 0, stream>>>(x, ln1_g + l*DIM, ln1_b + l*DIM, xn);
        k_gemm<0><<<dim3(DIM3/128, ROWS/128), 256, 0, stream>>>(
            xn, wqkvT + (size_t)l*DIM*DIM3, bqkv + (size_t)l*DIM3, qkvh, nullptr, DIM3, DIM);
        k_attn<<<dim3(8, HEADS, BATCH), 256, 0, stream>>>(qkvh, x);
        k_layernorm<<<ROWS, 256, 0, stream>>>(x, ln2_g + l*DIM, ln2_b + l*DIM, xn);
        k_gemm<1><<<dim3(DIMF/128, ROWS/128), 256, 0, stream>>>(
            xn, w1T + (size_t)l*DIM*DIMF, b1 + (size_t)l*DIMF, qkvh, nullptr, DIMF, DIM);
        k_gemm<2><<<dim3(DIM/128, ROWS/128), 256, 0, stream>>>(
            qkvh, w2T + (size_t)l*DIMF*DIM, b2 + (size_t)l*DIM, nullptr, x, DIM, DIMF);
    }
}